// Round 7
// baseline (3947.934 us; speedup 1.0000x reference)
//
#include <hip/hip_runtime.h>

// LSTM: B=1024, T=128, I=128, H=1024, O=64
// R8: A-fragments DIRECT global->register (asm global_load_dwordx4, counted),
//     LDS holds only B. R7 proved the counted-vmcnt pipeline (-226us) but is
//     LDS-BW-bound: 96KB reads + 32KB DMA writes per tile ~= 8.6us/step at
//     85 B/cyc. A-frag layout (row=l16, k=quad*8) loads directly from
//     row-major xb/h (16x64B segments, L2-resident). Per tile: 8 ds_reads
//     (B only), 2 B-DMA, 4 A-reg loads issued 1 tile ahead into the idle
//     reg set. Ledger: prologue B0,A0,A1,B1 -> phase0 vmcnt(6);
//     steady vmcnt(2) (leaves next B-DMA in flight); tail vmcnt(0).

#define B_DIM 1024
#define H_DIM 1024
#define I_DIM 128
#define T_DIM 128
#define XROW  (T_DIM * I_DIM)   // 16384
#define KDIM  (I_DIM + H_DIM)   // 1152
#define GDIM  (4 * H_DIM)       // 4096
#define O_DIM 64

typedef float f32x4 __attribute__((ext_vector_type(4)));
typedef short bf16x8 __attribute__((ext_vector_type(8)));
typedef unsigned short u16x8 __attribute__((ext_vector_type(8)));

__device__ __forceinline__ unsigned short f2bf(float f) {
    union { float f; unsigned int u; } v; v.f = f;
    unsigned int r = v.u + 0x7fffu + ((v.u >> 16) & 1u);  // RNE
    return (unsigned short)(r >> 16);
}
__device__ __forceinline__ float bf2f(unsigned short b) {
    union { unsigned int u; float f; } v; v.u = ((unsigned int)b) << 16;
    return v.f;
}
__device__ __forceinline__ float sigm(float x) { return 1.f / (1.f + __expf(-x)); }
__device__ __forceinline__ float tanh_fast(float x) { return 2.f / (1.f + __expf(-2.f * x)) - 1.f; }

// ---- prep: fp32 x -> bf16 ----
__global__ void conv_x(const float* __restrict__ x, unsigned short* __restrict__ xb) {
    size_t i = ((size_t)blockIdx.x * 256 + threadIdx.x) * 8;
    float4 v0 = *(const float4*)(x + i);
    float4 v1 = *(const float4*)(x + i + 4);
    u16x8 o;
    o[0] = f2bf(v0.x); o[1] = f2bf(v0.y); o[2] = f2bf(v0.z); o[3] = f2bf(v0.w);
    o[4] = f2bf(v1.x); o[5] = f2bf(v1.y); o[6] = f2bf(v1.z); o[7] = f2bf(v1.w);
    *(u16x8*)(xb + i) = o;
}

// ---- prep: gate-interleaved W'' [4096 x 1152] bf16 + combined bias ----
__global__ void build_w(const float* __restrict__ w_ih, const float* __restrict__ w_hh,
                        const float* __restrict__ b_ih, const float* __restrict__ b_hh,
                        unsigned short* __restrict__ W, float* __restrict__ bias) {
    int r = blockIdx.x;
    int nb = r >> 7, q = r & 127;
    int wh = q >> 6, w = q & 63;
    int gate = w >> 4, jl = w & 15;
    int orig = gate * 1024 + nb * 32 + wh * 16 + jl;
    for (int k = threadIdx.x; k < KDIM; k += 256) {
        float v = (k < I_DIM) ? w_ih[(size_t)orig * I_DIM + k]
                              : w_hh[(size_t)orig * H_DIM + (k - I_DIM)];
        W[(size_t)r * KDIM + k] = f2bf(v);
    }
    if (threadIdx.x == 0) bias[r] = b_ih[orig] + b_hh[orig];
}

// ---- prep: transpose w_fc [O][H] -> wT [H][O] so proj loads coalesce ----
__global__ void trans_wfc(const float* __restrict__ w_fc, float* __restrict__ wT) {
    int o = blockIdx.x;
    for (int k = threadIdx.x; k < H_DIM; k += 256)
        wT[(size_t)k * O_DIM + o] = w_fc[(size_t)o * H_DIM + k];
}

__global__ void zero_hc(unsigned short* __restrict__ h0, float* __restrict__ c) {
    int idx = blockIdx.x * 256 + threadIdx.x;
    h0[idx] = 0;
    c[idx] = 0.f;
}

// 8 ds_read_b128 of one B K-tile. OFF = buffer byte offset (0 / 16384).
#define READ_B(OFF) do {                                                          \
    asm volatile("ds_read_b128 %0, %1 offset:" OFF : "=v"(fb0) : "v"(aB0));       \
    asm volatile("ds_read_b128 %0, %1 offset:" OFF : "=v"(fb1) : "v"(aB1));       \
    asm volatile("ds_read_b128 %0, %1 offset:" OFF : "=v"(fb2) : "v"(aB2));       \
    asm volatile("ds_read_b128 %0, %1 offset:" OFF : "=v"(fb3) : "v"(aB3));       \
    asm volatile("ds_read_b128 %0, %1 offset:" OFF : "=v"(gb0) : "v"(aB0x));      \
    asm volatile("ds_read_b128 %0, %1 offset:" OFF : "=v"(gb1) : "v"(aB1x));      \
    asm volatile("ds_read_b128 %0, %1 offset:" OFF : "=v"(gb2) : "v"(aB2x));      \
    asm volatile("ds_read_b128 %0, %1 offset:" OFF : "=v"(gb3) : "v"(aB3x));      \
    asm volatile("s_waitcnt lgkmcnt(0)" ::: "memory");                            \
    __builtin_amdgcn_sched_barrier(0);                                            \
} while (0)

// 4 A-frag loads (one K-tile) into a register set, 1 tile ahead.
// T0=(mi0,ksl0) T1=(mi1,ksl0) T2=(mi0,ksl1) T3=(mi1,ksl1); O1 = O0+64.
#define ISSUE_A(T0, T1, T2, T3, V0, V1, BASE, O0, O1) do {                         \
    asm volatile("global_load_dwordx4 %0, %1, %2 offset:" O0                       \
                 : "=v"(T0) : "v"(V0), "s"(BASE));                                 \
    asm volatile("global_load_dwordx4 %0, %1, %2 offset:" O0                       \
                 : "=v"(T1) : "v"(V1), "s"(BASE));                                 \
    asm volatile("global_load_dwordx4 %0, %1, %2 offset:" O1                       \
                 : "=v"(T2) : "v"(V0), "s"(BASE));                                 \
    asm volatile("global_load_dwordx4 %0, %1, %2 offset:" O1                       \
                 : "=v"(T3) : "v"(V1), "s"(BASE));                                 \
} while (0)

#define MFMA_(a, b, c) c = __builtin_amdgcn_mfma_f32_16x16x32_bf16(a, b, c, 0, 0, 0)
#define MM_TILE(A0, A1, A2, A3) do {                                              \
    MFMA_(A0, fb0, acc[0][0]); MFMA_(A0, fb1, acc[0][1]);                         \
    MFMA_(A0, fb2, acc[0][2]); MFMA_(A0, fb3, acc[0][3]);                         \
    MFMA_(A1, fb0, acc[1][0]); MFMA_(A1, fb1, acc[1][1]);                         \
    MFMA_(A1, fb2, acc[1][2]); MFMA_(A1, fb3, acc[1][3]);                         \
    MFMA_(A2, gb0, acc[0][0]); MFMA_(A2, gb1, acc[0][1]);                         \
    MFMA_(A2, gb2, acc[0][2]); MFMA_(A2, gb3, acc[0][3]);                         \
    MFMA_(A3, gb0, acc[1][0]); MFMA_(A3, gb1, acc[1][1]);                         \
    MFMA_(A3, gb2, acc[1][2]); MFMA_(A3, gb3, acc[1][3]);                         \
} while (0)

// ---- per-timestep: 128x128 tile GEMM + fused LSTM cell epilogue ----
__global__ __launch_bounds__(512, 2)
void lstm_step(const unsigned short* __restrict__ xb,
               const unsigned short* __restrict__ W,
               const float* __restrict__ bias,
               const unsigned short* __restrict__ h_in,
               unsigned short* __restrict__ h_out,
               float* __restrict__ c_st,
               int t) {
    // B double buffer only: buf0 @0, buf1 @16384 bytes
    __shared__ __align__(16) unsigned short lds[2 * 8192];
    const int tid  = threadIdx.x;
    const int wv   = tid >> 6, lane = tid & 63;
    const int wm   = wv >> 1, wn = wv & 1;      // 4x2 wave grid over 128x128
    const int quad = lane >> 4, l16 = lane & 15;
    const int l7   = l16 & 7;
    const int bid = blockIdx.x;
    const int xcd = bid & 7;
    const int sl  = bid >> 3;            // 0..31
    const int nb  = xcd * 4 + (sl & 3);  // 0..31 : XCD x owns nb in [4x,4x+4)
    const int mb  = sl >> 2;             // 0..7

    // epilogue addressing + prefetch of bias and old cell state
    const int j  = nb * 32 + wn * 16 + l16;
    const int bb = nb * 128 + wn * 64 + l16;
    const float bi  = bias[bb +  0];
    const float bf_ = bias[bb + 16];
    const float bg  = bias[bb + 32];
    const float bo  = bias[bb + 48];
    float cold[2][4];
#pragma unroll
    for (int mi = 0; mi < 2; mi++)
#pragma unroll
        for (int r = 0; r < 4; r++) {
            const int brow = mb * 128 + wm * 32 + mi * 16 + quad * 4 + r;
            cold[mi][r] = c_st[(size_t)brow * H_DIM + j];
        }

    f32x4 acc[2][4];
#pragma unroll
    for (int i = 0; i < 2; i++)
#pragma unroll
        for (int jj = 0; jj < 4; jj++) acc[i][jj] = f32x4{0.f, 0.f, 0.f, 0.f};

    const int arow = lane >> 3;              // 0..7: row within 8-row chunk
    const int ag   = lane & 7;               // physical 16B group this lane fills
    const int colperm = ((ag ^ arow) << 3);  // swizzled source column (bf16 units)

    // stage one 64-wide B K-tile into buffer bsel: exactly 2 DMA loads/wave
    auto stageB = [&](int bsel, int ks) {
        const int kt = ks * 64;
        unsigned short* Bs_ = lds + bsel * 8192;
#pragma unroll
        for (int c4 = 0; c4 < 2; ++c4) {
            const int row0 = wv * 16 + c4 * 8;
            const int row  = row0 + arow;
            const unsigned short* srcB =
                W + (size_t)(nb * 128 + row) * KDIM + kt + colperm;
            __builtin_amdgcn_global_load_lds(
                (const __attribute__((address_space(1))) void*)srcB,
                (__attribute__((address_space(3))) void*)(&Bs_[row0 * 64]), 16, 0, 0);
        }
    };

    // B ds_read addresses (bytes): row stride 128, frag col = (quad^l7)<<4
    const unsigned lbase = (unsigned)(unsigned long long)
        (__attribute__((address_space(3))) void*)lds;
    const unsigned cp  = (unsigned)((quad ^ l7) << 4);
    const unsigned aB0 = lbase + (unsigned)((wn * 64 + l16) * 128) + cp;
    const unsigned aB1 = aB0 + 2048;
    const unsigned aB2 = aB0 + 4096;
    const unsigned aB3 = aB0 + 6144;
    const unsigned aB0x = aB0 ^ 64u, aB1x = aB1 ^ 64u;
    const unsigned aB2x = aB2 ^ 64u, aB3x = aB3 ^ 64u;
    bf16x8 fb0, fb1, fb2, fb3, gb0, gb1, gb2, gb3;

    // A-frag voffsets (bytes, 32-bit): row = mb*128 + wm*32 + mi*16 + l16,
    // k-col = quad*8 (+32 via offset:64; next tile via += 128B)
    const int rowA0 = mb * 128 + wm * 32 + l16;
    const int rowA1 = rowA0 + 16;
    unsigned voffX0 = (unsigned)((rowA0 * XROW + t * I_DIM + quad * 8) * 2);
    unsigned voffX1 = (unsigned)((rowA1 * XROW + t * I_DIM + quad * 8) * 2);
    unsigned voffH0 = (unsigned)((rowA0 * H_DIM + quad * 8) * 2);
    unsigned voffH1 = (unsigned)((rowA1 * H_DIM + quad * 8) * 2);
    bf16x8 pa0, pa1, pa2, pa3;   // set0: even tiles
    bf16x8 qa0, qa1, qa2, qa3;   // set1: odd tiles

    // ---- prologue: B0, A0, A1, B1  (12 outstanding) ----
    stageB(0, 0);
    ISSUE_A(pa0, pa1, pa2, pa3, voffX0, voffX1, xb, "0", "64");      // A0 (x cols 0..63)
    ISSUE_A(qa0, qa1, qa2, qa3, voffX0, voffX1, xb, "128", "192");   // A1 (x cols 64..127)
    stageB(1, 1);

    // ---- phase 0 (tile 0: buf0, set0) ----
    asm volatile("s_waitcnt vmcnt(6)" ::: "memory");   // retire B0,A0; leave A1,B1
    __builtin_amdgcn_s_barrier();
    READ_B("0");
    __builtin_amdgcn_s_barrier();
    stageB(0, 2);
    MM_TILE(pa0, pa1, pa2, pa3);

#pragma unroll 1
    for (int p = 0; p < 8; ++p) {
        // phase 2p+1 (buf1, set1); issue A(2p+2)->set0; stage B(2p+3)->buf1
        asm volatile("s_waitcnt vmcnt(2)" ::: "memory");
        __builtin_amdgcn_s_barrier();
        READ_B("16384");
        __builtin_amdgcn_s_barrier();
        ISSUE_A(pa0, pa1, pa2, pa3, voffH0, voffH1, h_in, "0", "64");
        voffH0 += 128; voffH1 += 128;
        stageB(1, 2 * p + 3);
        MM_TILE(qa0, qa1, qa2, qa3);

        // phase 2p+2 (buf0, set0); issue A(2p+3)->set1; stage B(2p+4) if any
        asm volatile("s_waitcnt vmcnt(2)" ::: "memory");
        __builtin_amdgcn_s_barrier();
        READ_B("0");
        __builtin_amdgcn_s_barrier();
        ISSUE_A(qa0, qa1, qa2, qa3, voffH0, voffH1, h_in, "0", "64");
        voffH0 += 128; voffH1 += 128;
        if (p < 7) stageB(0, 2 * p + 4);
        MM_TILE(pa0, pa1, pa2, pa3);
    }
    // ---- tail phase 17 (buf1, set1) ----
    asm volatile("s_waitcnt vmcnt(0)" ::: "memory");
    __builtin_amdgcn_s_barrier();
    READ_B("16384");
    MM_TILE(qa0, qa1, qa2, qa3);

    // epilogue: ni == gate (0:i 1:f 2:g 3:o), fully in-lane
#pragma unroll
    for (int mi = 0; mi < 2; mi++) {
#pragma unroll
        for (int r = 0; r < 4; r++) {
            const int brow = mb * 128 + wm * 32 + mi * 16 + quad * 4 + r;
            const float gi = acc[mi][0][r] + bi;
            const float gf = acc[mi][1][r] + bf_;
            const float gg = acc[mi][2][r] + bg;
            const float go = acc[mi][3][r] + bo;
            const size_t idx = (size_t)brow * H_DIM + j;
            const float cn = sigm(gf) * cold[mi][r] + sigm(gi) * tanh_fast(gg);
            c_st[idx] = cn;
            h_out[idx] = f2bf(sigm(go) * tanh_fast(cn));
        }
    }
}

// ---- final projection: 4 batch rows per block, lane = output dim ----
__global__ void proj(const unsigned short* __restrict__ h,
                     const float* __restrict__ wT,
                     const float* __restrict__ b_fc,
                     float* __restrict__ out) {
    __shared__ float hs[4][H_DIM];
    const int tid = threadIdx.x, wv = tid >> 6, o = tid & 63;
    const int b = blockIdx.x * 4 + wv;
    const unsigned short* hrow = h + (size_t)b * H_DIM;
#pragma unroll
    for (int i = 0; i < 2; ++i) {
        const int k0 = i * 512 + o * 8;
        u16x8 v = *(const u16x8*)(hrow + k0);
        float4 f0 = {bf2f((unsigned short)v[0]), bf2f((unsigned short)v[1]),
                     bf2f((unsigned short)v[2]), bf2f((unsigned short)v[3])};
        float4 f1 = {bf2f((unsigned short)v[4]), bf2f((unsigned short)v[5]),
                     bf2f((unsigned short)v[6]), bf2f((unsigned short)v[7])};
        *(float4*)&hs[wv][k0]     = f0;
        *(float4*)&hs[wv][k0 + 4] = f1;
    }
    float s0 = 0.f, s1 = 0.f, s2 = 0.f, s3 = 0.f;
#pragma unroll 4
    for (int k4 = 0; k4 < H_DIM / 4; ++k4) {
        float4 hv = *(const float4*)&hs[wv][k4 * 4];
        const float* wp = wT + (size_t)k4 * 4 * O_DIM + o;
        s0 += hv.x * wp[0 * O_DIM];
        s1 += hv.y * wp[1 * O_DIM];
        s2 += hv.z * wp[2 * O_DIM];
        s3 += hv.w * wp[3 * O_DIM];
    }
    out[(size_t)b * O_DIM + o] = s0 + s1 + s2 + s3 + b_fc[o];
}

extern "C" void kernel_launch(void* const* d_in, const int* in_sizes, int n_in,
                              void* d_out, int out_size, void* d_ws, size_t ws_size,
                              hipStream_t stream) {
    const float* x    = (const float*)d_in[0];
    const float* w_ih = (const float*)d_in[1];
    const float* w_hh = (const float*)d_in[2];
    const float* b_ih = (const float*)d_in[3];
    const float* b_hh = (const float*)d_in[4];
    const float* w_fc = (const float*)d_in[5];
    const float* b_fc = (const float*)d_in[6];
    float* out = (float*)d_out;

    char* ws = (char*)d_ws;
    size_t off = 0;
    unsigned short* xb = (unsigned short*)(ws + off); off += (size_t)B_DIM * XROW * 2;
    unsigned short* W  = (unsigned short*)(ws + off); off += (size_t)GDIM * KDIM * 2;
    float* bias        = (float*)(ws + off);          off += (size_t)GDIM * 4;
    unsigned short* h0 = (unsigned short*)(ws + off); off += (size_t)B_DIM * H_DIM * 2;
    unsigned short* h1 = (unsigned short*)(ws + off); off += (size_t)B_DIM * H_DIM * 2;
    float* c           = (float*)(ws + off);          off += (size_t)B_DIM * H_DIM * 4;
    float* wT          = (float*)(ws + off);          off += (size_t)H_DIM * O_DIM * 4;

    conv_x<<<8192, 256, 0, stream>>>(x, xb);
    build_w<<<GDIM, 256, 0, stream>>>(w_ih, w_hh, b_ih, b_hh, W, bias);
    trans_wfc<<<O_DIM, 256, 0, stream>>>(w_fc, wT);
    zero_hc<<<4096, 256, 0, stream>>>(h0, c);

    for (int t = 0; t < T_DIM; ++t) {
        const unsigned short* hin = (t & 1) ? h1 : h0;
        unsigned short* hout      = (t & 1) ? h0 : h1;
        lstm_step<<<256, 512, 0, stream>>>(xb, W, bias, hin, hout, c, t);
    }
    // t=127 wrote h0
    proj<<<256, 256, 0, stream>>>(h0, wT, b_fc, out);
}

// Round 8
// 2104.314 us; speedup vs baseline: 1.8761x; 1.8761x over previous
//
#include <hip/hip_runtime.h>

// LSTM: B=1024, T=128, I=128, H=1024, O=64
// R9: REVERT R8 (direct A-to-reg: 2x regression — scattered 16-segment
//     VMEM txns and/or VGPR spill). Base = R7 (1976us, verified).
//     CHANGE: 4 waves x 64x64 wave-tiles (was 8 x 32x64) in the same
//     128x128 block. LDS read traffic per tile drops 96KB -> 64KB/CU
//     (A-dup x2 + B-dup x2 instead of x2/x4) — attacks the measured
//     floor (LDS reads ~8.5us/step at 85 B/cyc). MFMA pipe time per SIMD
//     unchanged (1 wave x 32 MFMA == 2 waves x 16). R7's counted-vmcnt
//     ledger kept verbatim, scaled to 8 loads/stage (steady vmcnt(8));
//     split lgkmcnt(8) hides ds latency under half-1 MFMAs.

#define B_DIM 1024
#define H_DIM 1024
#define I_DIM 128
#define T_DIM 128
#define XROW  (T_DIM * I_DIM)   // 16384
#define KDIM  (I_DIM + H_DIM)   // 1152
#define GDIM  (4 * H_DIM)       // 4096
#define O_DIM 64

typedef float f32x4 __attribute__((ext_vector_type(4)));
typedef short bf16x8 __attribute__((ext_vector_type(8)));
typedef unsigned short u16x8 __attribute__((ext_vector_type(8)));

__device__ __forceinline__ unsigned short f2bf(float f) {
    union { float f; unsigned int u; } v; v.f = f;
    unsigned int r = v.u + 0x7fffu + ((v.u >> 16) & 1u);  // RNE
    return (unsigned short)(r >> 16);
}
__device__ __forceinline__ float bf2f(unsigned short b) {
    union { unsigned int u; float f; } v; v.u = ((unsigned int)b) << 16;
    return v.f;
}
__device__ __forceinline__ float sigm(float x) { return 1.f / (1.f + __expf(-x)); }
__device__ __forceinline__ float tanh_fast(float x) { return 2.f / (1.f + __expf(-2.f * x)) - 1.f; }

// ---- prep: fp32 x -> bf16 ----
__global__ void conv_x(const float* __restrict__ x, unsigned short* __restrict__ xb) {
    size_t i = ((size_t)blockIdx.x * 256 + threadIdx.x) * 8;
    float4 v0 = *(const float4*)(x + i);
    float4 v1 = *(const float4*)(x + i + 4);
    u16x8 o;
    o[0] = f2bf(v0.x); o[1] = f2bf(v0.y); o[2] = f2bf(v0.z); o[3] = f2bf(v0.w);
    o[4] = f2bf(v1.x); o[5] = f2bf(v1.y); o[6] = f2bf(v1.z); o[7] = f2bf(v1.w);
    *(u16x8*)(xb + i) = o;
}

// ---- prep: gate-interleaved W'' [4096 x 1152] bf16 + combined bias ----
__global__ void build_w(const float* __restrict__ w_ih, const float* __restrict__ w_hh,
                        const float* __restrict__ b_ih, const float* __restrict__ b_hh,
                        unsigned short* __restrict__ W, float* __restrict__ bias) {
    int r = blockIdx.x;
    int nb = r >> 7, q = r & 127;
    int wh = q >> 6, w = q & 63;
    int gate = w >> 4, jl = w & 15;
    int orig = gate * 1024 + nb * 32 + wh * 16 + jl;
    for (int k = threadIdx.x; k < KDIM; k += 256) {
        float v = (k < I_DIM) ? w_ih[(size_t)orig * I_DIM + k]
                              : w_hh[(size_t)orig * H_DIM + (k - I_DIM)];
        W[(size_t)r * KDIM + k] = f2bf(v);
    }
    if (threadIdx.x == 0) bias[r] = b_ih[orig] + b_hh[orig];
}

// ---- prep: transpose w_fc [O][H] -> wT [H][O] so proj loads coalesce ----
__global__ void trans_wfc(const float* __restrict__ w_fc, float* __restrict__ wT) {
    int o = blockIdx.x;
    for (int k = threadIdx.x; k < H_DIM; k += 256)
        wT[(size_t)k * O_DIM + o] = w_fc[(size_t)o * H_DIM + k];
}

__global__ void zero_hc(unsigned short* __restrict__ h0, float* __restrict__ c) {
    int idx = blockIdx.x * 256 + threadIdx.x;
    h0[idx] = 0;
    c[idx] = 0.f;
}

// 16 ds_read_b128 of one K-tile (A 64 rows + B 64 rows for this wave).
// OFF = buffer byte offset ("0" / "32768"). Issue kk=0 A+B (8), then kk=32
// via addr^64; wait lgkmcnt(8) -> first 8 ready; MFMA half1 runs while the
// rest land; lgkmcnt(0) before half2 (rule #18 fences after each wait).
#define READ_TILE(OFF) do {                                                       \
    asm volatile("ds_read_b128 %0, %1 offset:" OFF : "=v"(fa0) : "v"(aA0));       \
    asm volatile("ds_read_b128 %0, %1 offset:" OFF : "=v"(fa1) : "v"(aA1));       \
    asm volatile("ds_read_b128 %0, %1 offset:" OFF : "=v"(fa2) : "v"(aA2));       \
    asm volatile("ds_read_b128 %0, %1 offset:" OFF : "=v"(fa3) : "v"(aA3));       \
    asm volatile("ds_read_b128 %0, %1 offset:" OFF : "=v"(fb0) : "v"(aB0));       \
    asm volatile("ds_read_b128 %0, %1 offset:" OFF : "=v"(fb1) : "v"(aB1));       \
    asm volatile("ds_read_b128 %0, %1 offset:" OFF : "=v"(fb2) : "v"(aB2));       \
    asm volatile("ds_read_b128 %0, %1 offset:" OFF : "=v"(fb3) : "v"(aB3));       \
    asm volatile("ds_read_b128 %0, %1 offset:" OFF : "=v"(ga0) : "v"(aA0 ^ 64u)); \
    asm volatile("ds_read_b128 %0, %1 offset:" OFF : "=v"(ga1) : "v"(aA1 ^ 64u)); \
    asm volatile("ds_read_b128 %0, %1 offset:" OFF : "=v"(ga2) : "v"(aA2 ^ 64u)); \
    asm volatile("ds_read_b128 %0, %1 offset:" OFF : "=v"(ga3) : "v"(aA3 ^ 64u)); \
    asm volatile("ds_read_b128 %0, %1 offset:" OFF : "=v"(gb0) : "v"(aB0 ^ 64u)); \
    asm volatile("ds_read_b128 %0, %1 offset:" OFF : "=v"(gb1) : "v"(aB1 ^ 64u)); \
    asm volatile("ds_read_b128 %0, %1 offset:" OFF : "=v"(gb2) : "v"(aB2 ^ 64u)); \
    asm volatile("ds_read_b128 %0, %1 offset:" OFF : "=v"(gb3) : "v"(aB3 ^ 64u)); \
} while (0)

#define MFMA_(a, b, c) c = __builtin_amdgcn_mfma_f32_16x16x32_bf16(a, b, c, 0, 0, 0)

#define MM_HALF1() do {                                                           \
    MFMA_(fa0, fb0, acc[0][0]); MFMA_(fa0, fb1, acc[0][1]);                       \
    MFMA_(fa0, fb2, acc[0][2]); MFMA_(fa0, fb3, acc[0][3]);                       \
    MFMA_(fa1, fb0, acc[1][0]); MFMA_(fa1, fb1, acc[1][1]);                       \
    MFMA_(fa1, fb2, acc[1][2]); MFMA_(fa1, fb3, acc[1][3]);                       \
    MFMA_(fa2, fb0, acc[2][0]); MFMA_(fa2, fb1, acc[2][1]);                       \
    MFMA_(fa2, fb2, acc[2][2]); MFMA_(fa2, fb3, acc[2][3]);                       \
    MFMA_(fa3, fb0, acc[3][0]); MFMA_(fa3, fb1, acc[3][1]);                       \
    MFMA_(fa3, fb2, acc[3][2]); MFMA_(fa3, fb3, acc[3][3]);                       \
} while (0)
#define MM_HALF2() do {                                                           \
    MFMA_(ga0, gb0, acc[0][0]); MFMA_(ga0, gb1, acc[0][1]);                       \
    MFMA_(ga0, gb2, acc[0][2]); MFMA_(ga0, gb3, acc[0][3]);                       \
    MFMA_(ga1, gb0, acc[1][0]); MFMA_(ga1, gb1, acc[1][1]);                       \
    MFMA_(ga1, gb2, acc[1][2]); MFMA_(ga1, gb3, acc[1][3]);                       \
    MFMA_(ga2, gb0, acc[2][0]); MFMA_(ga2, gb1, acc[2][1]);                       \
    MFMA_(ga2, gb2, acc[2][2]); MFMA_(ga2, gb3, acc[2][3]);                       \
    MFMA_(ga3, gb0, acc[3][0]); MFMA_(ga3, gb1, acc[3][1]);                       \
    MFMA_(ga3, gb2, acc[3][2]); MFMA_(ga3, gb3, acc[3][3]);                       \
} while (0)

// one full tile: reads + split waits + two MFMA halves
#define DO_TILE(OFF) do {                                                         \
    READ_TILE(OFF);                                                               \
    asm volatile("s_waitcnt lgkmcnt(8)" ::: "memory");                            \
    __builtin_amdgcn_sched_barrier(0);                                            \
    MM_HALF1();                                                                   \
    asm volatile("s_waitcnt lgkmcnt(0)" ::: "memory");                            \
    __builtin_amdgcn_sched_barrier(0);                                            \
    MM_HALF2();                                                                   \
} while (0)

// ---- per-timestep: 128x128 block, 4 waves x 64x64, fused LSTM epilogue ----
__global__ __launch_bounds__(256, 1)
void lstm_step(const unsigned short* __restrict__ xb,
               const unsigned short* __restrict__ W,
               const float* __restrict__ bias,
               const unsigned short* __restrict__ h_in,
               unsigned short* __restrict__ h_out,
               float* __restrict__ c_st,
               int t) {
    // buffer i at byte 32768*i; within buffer: A[0,16384) B[16384,32768)
    __shared__ __align__(16) unsigned short lds[2 * 16384];
    const int tid  = threadIdx.x;
    const int wv   = tid >> 6, lane = tid & 63;
    const int wm   = wv >> 1, wn = wv & 1;      // 2x2 wave grid, 64x64 each
    const int quad = lane >> 4, l16 = lane & 15;
    const int l7   = l16 & 7;
    const int bid = blockIdx.x;
    const int xcd = bid & 7;
    const int sl  = bid >> 3;            // 0..31
    const int nb  = xcd * 4 + (sl & 3);  // 0..31 : XCD x owns nb in [4x,4x+4)
    const int mb  = sl >> 2;             // 0..7

    // epilogue addressing: wave covers cols [wn*64, wn*64+64) = 16 j x 4 gates
    const int j  = nb * 32 + wn * 16 + l16;
    const int bb = nb * 128 + wn * 64 + l16;
    const float bi  = bias[bb +  0];
    const float bf_ = bias[bb + 16];
    const float bg  = bias[bb + 32];
    const float bo  = bias[bb + 48];
    float cold[4][4];
#pragma unroll
    for (int mi = 0; mi < 4; mi++)
#pragma unroll
        for (int r = 0; r < 4; r++) {
            const int brow = mb * 128 + wm * 64 + mi * 16 + quad * 4 + r;
            cold[mi][r] = c_st[(size_t)brow * H_DIM + j];
        }

    f32x4 acc[4][4];
#pragma unroll
    for (int i = 0; i < 4; i++)
#pragma unroll
        for (int jj = 0; jj < 4; jj++) acc[i][jj] = f32x4{0.f, 0.f, 0.f, 0.f};

    const int arow = lane >> 3;              // 0..7: row within 8-row chunk
    const int ag   = lane & 7;               // physical 16B group this lane fills
    const int colperm = ((ag ^ arow) << 3);  // swizzled source column (bf16 units)

    // stage one 64-wide K-tile into buffer bsel: exactly 8 DMA loads/wave
    // (4 A-chunks + 4 B-chunks of 8 rows; 4 waves cover 128 rows each of A,B)
    auto stage = [&](int bsel, int ks) {
        const int kt = ks * 64;
        unsigned short* As_ = lds + bsel * 16384;
        unsigned short* Bs_ = As_ + 8192;
#pragma unroll
        for (int c4 = 0; c4 < 4; ++c4) {
            const int row0 = wv * 32 + c4 * 8;
            const int row  = row0 + arow;
            const unsigned short* srcA =
                (kt < I_DIM)
                    ? xb   + (size_t)(mb * 128 + row) * XROW + t * I_DIM + kt + colperm
                    : h_in + (size_t)(mb * 128 + row) * H_DIM + (kt - I_DIM) + colperm;
            __builtin_amdgcn_global_load_lds(
                (const __attribute__((address_space(1))) void*)srcA,
                (__attribute__((address_space(3))) void*)(&As_[row0 * 64]), 16, 0, 0);
        }
#pragma unroll
        for (int c4 = 0; c4 < 4; ++c4) {
            const int row0 = wv * 32 + c4 * 8;
            const int row  = row0 + arow;
            const unsigned short* srcB =
                W + (size_t)(nb * 128 + row) * KDIM + kt + colperm;
            __builtin_amdgcn_global_load_lds(
                (const __attribute__((address_space(1))) void*)srcB,
                (__attribute__((address_space(3))) void*)(&Bs_[row0 * 64]), 16, 0, 0);
        }
    };

    // asm ds_read addresses (bytes): row stride 128, frag col = (quad^l7)<<4
    const unsigned lbase = (unsigned)(unsigned long long)
        (__attribute__((address_space(3))) void*)lds;
    const unsigned cp  = (unsigned)((quad ^ l7) << 4);
    const unsigned aA0 = lbase + (unsigned)((wm * 64 + l16) * 128) + cp;
    const unsigned aA1 = aA0 + 2048;
    const unsigned aA2 = aA0 + 4096;
    const unsigned aA3 = aA0 + 6144;
    const unsigned aB0 = lbase + 16384u + (unsigned)((wn * 64 + l16) * 128) + cp;
    const unsigned aB1 = aB0 + 2048;
    const unsigned aB2 = aB0 + 4096;
    const unsigned aB3 = aB0 + 6144;
    bf16x8 fa0, fa1, fa2, fa3, fb0, fb1, fb2, fb3;
    bf16x8 ga0, ga1, ga2, ga3, gb0, gb1, gb2, gb3;

    // ---- counted-vmcnt pipeline (R7 skeleton, 8 loads/wave/tile) ----
    stage(0, 0);
    stage(1, 1);
    // phase 0 (tile 0, buf0): retire t0's 8, leave t1's 8 in flight
    asm volatile("s_waitcnt vmcnt(8)" ::: "memory");
    __builtin_amdgcn_s_barrier();
    READ_TILE("0");
    asm volatile("s_waitcnt lgkmcnt(0)" ::: "memory");
    __builtin_amdgcn_sched_barrier(0);
    __builtin_amdgcn_s_barrier();        // all waves done reading buf0
    stage(0, 2);                         // overwrite buf0 (t1 DMA still flying)
    MM_HALF1();
    MM_HALF2();

#pragma unroll 1
    for (int p = 0; p < 8; ++p) {
        // tile 2p+1 (buf1)
        asm volatile("s_waitcnt vmcnt(8)" ::: "memory");
        __builtin_amdgcn_s_barrier();
        READ_TILE("32768");
        asm volatile("s_waitcnt lgkmcnt(0)" ::: "memory");
        __builtin_amdgcn_sched_barrier(0);
        __builtin_amdgcn_s_barrier();
        stage(1, 2 * p + 3);             // <= 17
        MM_HALF1();
        MM_HALF2();

        // tile 2p+2 (buf0)
        asm volatile("s_waitcnt vmcnt(8)" ::: "memory");
        __builtin_amdgcn_s_barrier();
        READ_TILE("0");
        asm volatile("s_waitcnt lgkmcnt(0)" ::: "memory");
        __builtin_amdgcn_sched_barrier(0);
        __builtin_amdgcn_s_barrier();
        if (p < 7) stage(0, 2 * p + 4);  // <= 16
        MM_HALF1();
        MM_HALF2();
    }
    // tail: tile 17 (buf1), no more staging; split lgkm OK (no overwrite race)
    asm volatile("s_waitcnt vmcnt(0)" ::: "memory");
    __builtin_amdgcn_s_barrier();
    DO_TILE("32768");

    // epilogue: ni == gate (0:i 1:f 2:g 3:o), fully in-lane
#pragma unroll
    for (int mi = 0; mi < 4; mi++) {
#pragma unroll
        for (int r = 0; r < 4; r++) {
            const int brow = mb * 128 + wm * 64 + mi * 16 + quad * 4 + r;
            const float gi = acc[mi][0][r] + bi;
            const float gf = acc[mi][1][r] + bf_;
            const float gg = acc[mi][2][r] + bg;
            const float go = acc[mi][3][r] + bo;
            const size_t idx = (size_t)brow * H_DIM + j;
            const float cn = sigm(gf) * cold[mi][r] + sigm(gi) * tanh_fast(gg);
            c_st[idx] = cn;
            h_out[idx] = f2bf(sigm(go) * tanh_fast(cn));
        }
    }
}

// ---- final projection: 4 batch rows per block, lane = output dim ----
__global__ void proj(const unsigned short* __restrict__ h,
                     const float* __restrict__ wT,
                     const float* __restrict__ b_fc,
                     float* __restrict__ out) {
    __shared__ float hs[4][H_DIM];
    const int tid = threadIdx.x, wv = tid >> 6, o = tid & 63;
    const int b = blockIdx.x * 4 + wv;
    const unsigned short* hrow = h + (size_t)b * H_DIM;
#pragma unroll
    for (int i = 0; i < 2; ++i) {
        const int k0 = i * 512 + o * 8;
        u16x8 v = *(const u16x8*)(hrow + k0);
        float4 f0 = {bf2f((unsigned short)v[0]), bf2f((unsigned short)v[1]),
                     bf2f((unsigned short)v[2]), bf2f((unsigned short)v[3])};
        float4 f1 = {bf2f((unsigned short)v[4]), bf2f((unsigned short)v[5]),
                     bf2f((unsigned short)v[6]), bf2f((unsigned short)v[7])};
        *(float4*)&hs[wv][k0]     = f0;
        *(float4*)&hs[wv][k0 + 4] = f1;
    }
    float s0 = 0.f, s1 = 0.f, s2 = 0.f, s3 = 0.f;
#pragma unroll 4
    for (int k4 = 0; k4 < H_DIM / 4; ++k4) {
        float4 hv = *(const float4*)&hs[wv][k4 * 4];
        const float* wp = wT + (size_t)k4 * 4 * O_DIM + o;
        s0 += hv.x * wp[0 * O_DIM];
        s1 += hv.y * wp[1 * O_DIM];
        s2 += hv.z * wp[2 * O_DIM];
        s3 += hv.w * wp[3 * O_DIM];
    }
    out[(size_t)b * O_DIM + o] = s0 + s1 + s2 + s3 + b_fc[o];
}

extern "C" void kernel_launch(void* const* d_in, const int* in_sizes, int n_in,
                              void* d_out, int out_size, void* d_ws, size_t ws_size,
                              hipStream_t stream) {
    const float* x    = (const float*)d_in[0];
    const float* w_ih = (const float*)d_in[1];
    const float* w_hh = (const float*)d_in[2];
    const float* b_ih = (const float*)d_in[3];
    const float* b_hh = (const float*)d_in[4];
    const float* w_fc = (const float*)d_in[5];
    const float* b_fc = (const float*)d_in[6];
    float* out = (float*)d_out;

    char* ws = (char*)d_ws;
    size_t off = 0;
    unsigned short* xb = (unsigned short*)(ws + off); off += (size_t)B_DIM * XROW * 2;
    unsigned short* W  = (unsigned short*)(ws + off); off += (size_t)GDIM * KDIM * 2;
    float* bias        = (float*)(ws + off);          off += (size_t)GDIM * 4;
    unsigned short* h0 = (unsigned short*)(ws + off); off += (size_t)B_DIM * H_DIM * 2;
    unsigned short* h1 = (unsigned short*)(ws + off); off += (size_t)B_DIM * H_DIM * 2;
    float* c           = (float*)(ws + off);          off += (size_t)B_DIM * H_DIM * 4;
    float* wT          = (float*)(ws + off);          off += (size_t)H_DIM * O_DIM * 4;

    conv_x<<<8192, 256, 0, stream>>>(x, xb);
    build_w<<<GDIM, 256, 0, stream>>>(w_ih, w_hh, b_ih, b_hh, W, bias);
    trans_wfc<<<O_DIM, 256, 0, stream>>>(w_fc, wT);
    zero_hc<<<4096, 256, 0, stream>>>(h0, c);

    for (int t = 0; t < T_DIM; ++t) {
        const unsigned short* hin = (t & 1) ? h1 : h0;
        unsigned short* hout      = (t & 1) ? h0 : h1;
        lstm_step<<<256, 256, 0, stream>>>(xb, W, bias, hin, hout, c, t);
    }
    // t=127 wrote h0
    proj<<<256, 256, 0, stream>>>(h0, wT, b_fc, out);
}